// Round 1
// baseline (365.460 us; speedup 1.0000x reference)
//
#include <hip/hip_runtime.h>

// TreeAttentionV2: B=8, T=1024, C=1024 (L=4,R=256), H=16, hd=64.
// Pipeline (all fp16 MFMA, fp32 accumulate):
//   1. conv_x:      x fp32 (8192x1024) -> xh fp16
//   2. tconv:       w_attn fp32 (1024x3072) -> waT fp16 (3072x1024)   [B^T for GEMM]
//   3. tconv:       w_proj fp32 (1024x1024) -> wpT fp16 (1024x1024)
//   4. gemm<f16>:   qkv = xh @ waT^T + b_attn  -> fp16 (8192x3072)
//   5. vtrans:      v section -> vT (128 heads)(64 x 1024)            [V^T for PV MFMA]
//   6. attn:        per (bh, 32-row q tile): S=QK^T/8 -> exp -> LDS(64KB, xor-swizzled)
//                   rowsum -> p=relu(e/l - 1e-3) -> y = P@V  -> y fp16 (8192x1024)
//   7. gemm<f32>:   out = y @ wpT^T + b_proj -> fp32 d_out
//
// Workspace layout (needs >= 92,274,688 B):
//   [0, 48M)   qkv fp16
//   [48M,64M)  vT  fp16
//   [64M,80M)  xh fp16 (reused as y after gemm1 consumes it)
//   [80M,86M)  waT fp16
//   [86M,88M)  wpT fp16

typedef _Float16 half8 __attribute__((ext_vector_type(8)));
typedef _Float16 half4_t __attribute__((ext_vector_type(4)));
typedef float floatx4 __attribute__((ext_vector_type(4)));

__device__ __forceinline__ void gl2lds16(const void* gsrc, void* lds) {
    __builtin_amdgcn_global_load_lds(
        (const __attribute__((address_space(1))) unsigned int*)gsrc,
        (__attribute__((address_space(3))) unsigned int*)lds,
        16, 0, 0);
}

// ---------------- elementwise convert fp32 -> fp16 ----------------
__global__ __launch_bounds__(256) void conv_x(const float4* __restrict__ in,
                                              _Float16* __restrict__ out, int n4) {
    int idx = blockIdx.x * blockDim.x + threadIdx.x;
    int stride = gridDim.x * blockDim.x;
    for (int i = idx; i < n4; i += stride) {
        float4 v = in[i];
        half4_t h = { (_Float16)v.x, (_Float16)v.y, (_Float16)v.z, (_Float16)v.w };
        *(half4_t*)(out + (size_t)i * 4) = h;
    }
}

// ------------- transpose + convert: out[n][k] = in[k][n] ----------
// in: (R rows x C cols) fp32, out: (C x R) fp16. grid (C/64, R/64), 256 thr.
__global__ __launch_bounds__(256) void tconv(const float* __restrict__ in,
                                             _Float16* __restrict__ out, int R, int C) {
    __shared__ _Float16 t[64 * 65];
    int bx = blockIdx.x, by = blockIdx.y;
#pragma unroll
    for (int it = 0; it < 16; ++it) {
        int idx = it * 256 + threadIdx.x;
        int r = idx >> 6, c = idx & 63;
        t[c * 65 + r] = (_Float16)in[(size_t)(by * 64 + r) * C + bx * 64 + c];
    }
    __syncthreads();
#pragma unroll
    for (int it = 0; it < 16; ++it) {
        int idx = it * 256 + threadIdx.x;
        int rn = idx >> 6, ck = idx & 63;
        out[(size_t)(bx * 64 + rn) * R + by * 64 + ck] = t[rn * 65 + ck];
    }
}

// ------------- V transpose: vT[bh*64+d][t] = qkv[b,t, 2048+h*64+d] -------------
__global__ __launch_bounds__(256) void vtrans(const _Float16* __restrict__ qkv,
                                              _Float16* __restrict__ vT) {
    __shared__ _Float16 t[64 * 65];
    int t0 = blockIdx.x * 64;
    int bh = blockIdx.y;
    int b = bh >> 4, h = bh & 15;
#pragma unroll
    for (int it = 0; it < 16; ++it) {
        int idx = it * 256 + threadIdx.x;
        int tt = idx >> 6, d = idx & 63;
        t[d * 65 + tt] = qkv[(size_t)(b * 1024 + t0 + tt) * 3072 + 2048 + h * 64 + d];
    }
    __syncthreads();
#pragma unroll
    for (int it = 0; it < 16; ++it) {
        int idx = it * 256 + threadIdx.x;
        int dd = idx >> 6, tt = idx & 63;
        vT[(size_t)(bh * 64 + dd) * 1024 + t0 + tt] = t[dd * 65 + tt];
    }
}

// ------------- m97-style GEMM: C(MxN) = A(MxK) * BT(NxK)^T + bias -------------
// K = 1024 fixed. 128x128 block tile, 256 threads = 4 waves (2x2 of 64x64).
template <bool F16OUT>
__global__ __launch_bounds__(256) void gemm_tn(const _Float16* __restrict__ A,
                                               const _Float16* __restrict__ BT,
                                               const float* __restrict__ bias,
                                               void* __restrict__ Cout, int N) {
    constexpr int K = 1024;
    __shared__ __attribute__((aligned(16))) _Float16 sA[128 * 32];
    __shared__ __attribute__((aligned(16))) _Float16 sB[128 * 32];
    int tid = threadIdx.x;
    int W = tid >> 6, lane = tid & 63, quad = lane >> 4, l15 = lane & 15;
    int m0 = blockIdx.y * 128, n0 = blockIdx.x * 128;
    int wr = (W >> 1) * 64, wc = (W & 1) * 64;
    floatx4 acc[4][4] = {};

    for (int kt = 0; kt < K / 32; ++kt) {
        int k0 = kt * 32;
#pragma unroll
        for (int rho = 0; rho < 2; ++rho) {
            int lin = rho * 256 + tid;                 // 16B chunk id, tile row-major
            const _Float16* gA = A + (size_t)(m0 + (lin >> 2)) * K + k0 + (lin & 3) * 8;
            const _Float16* gB = BT + (size_t)(n0 + (lin >> 2)) * K + k0 + (lin & 3) * 8;
            int ldsoff = __builtin_amdgcn_readfirstlane((rho * 256 + W * 64) * 16);
            gl2lds16(gA, (char*)sA + ldsoff);
            gl2lds16(gB, (char*)sB + ldsoff);
        }
        __syncthreads();
        half8 a[4], b[4];
#pragma unroll
        for (int rf = 0; rf < 4; ++rf)
            a[rf] = *(const half8*)(sA + (wr + rf * 16 + l15) * 32 + quad * 8);
#pragma unroll
        for (int cf = 0; cf < 4; ++cf)
            b[cf] = *(const half8*)(sB + (wc + cf * 16 + l15) * 32 + quad * 8);
#pragma unroll
        for (int rf = 0; rf < 4; ++rf)
#pragma unroll
            for (int cf = 0; cf < 4; ++cf)
                acc[rf][cf] = __builtin_amdgcn_mfma_f32_16x16x32_f16(a[rf], b[cf], acc[rf][cf], 0, 0, 0);
        __syncthreads();
    }
    // epilogue: C/D layout col=lane&15, row=quad*4+reg
#pragma unroll
    for (int cf = 0; cf < 4; ++cf) {
        int gn = n0 + wc + cf * 16 + l15;
        float bv = bias[gn];
#pragma unroll
        for (int rf = 0; rf < 4; ++rf) {
            int gmBase = m0 + wr + rf * 16 + quad * 4;
#pragma unroll
            for (int r = 0; r < 4; ++r) {
                float v = acc[rf][cf][r] + bv;
                size_t off = (size_t)(gmBase + r) * N + gn;
                if (F16OUT) ((_Float16*)Cout)[off] = (_Float16)v;
                else        ((float*)Cout)[off] = v;
            }
        }
    }
}

// ------------------------------- attention -------------------------------
// grid (32 q-tiles, 128 bh), 256 threads = 4 waves; wave w owns k-cols [w*256, w*256+256)
// LDS: E = 32 rows x 1024 cols fp16 (64KB exactly), xor-swizzled rows.
__device__ __forceinline__ int esw(int row, int colByte) {
    return row * 2048 + (colByte ^ ((row & 7) << 4));
}

__global__ __launch_bounds__(256) void attn(const _Float16* __restrict__ qkv,
                                            const _Float16* __restrict__ vT,
                                            _Float16* __restrict__ y) {
    __shared__ __attribute__((aligned(16))) _Float16 E[32 * 1024];
    char* Eb = (char*)E;
    int tid = threadIdx.x;
    int W = tid >> 6, lane = tid & 63, quad = lane >> 4, l15 = lane & 15;
    int qt = blockIdx.x, bh = blockIdx.y;
    int b = bh >> 4, h = bh & 15;
    int q0 = qt * 32;

    // --- load Q fragments (A-layout: m=lane&15, k=quad*8+j) ---
    half8 aq[2][2];
#pragma unroll
    for (int rf = 0; rf < 2; ++rf)
#pragma unroll
        for (int ks = 0; ks < 2; ++ks)
            aq[rf][ks] = *(const half8*)(qkv + (size_t)(b * 1024 + q0 + rf * 16 + l15) * 3072 +
                                         h * 64 + ks * 32 + quad * 8);

    // --- S = QK^T/8, e = exp(s), store fp16 into LDS ---
#pragma unroll 4
    for (int cf = 0; cf < 16; ++cf) {
        int c0 = W * 256 + cf * 16;
        int tk = c0 + l15;
        const _Float16* kp = qkv + (size_t)(b * 1024 + tk) * 3072 + 1024 + h * 64;
        half8 bk0 = *(const half8*)(kp + quad * 8);
        half8 bk1 = *(const half8*)(kp + 32 + quad * 8);
#pragma unroll
        for (int rf = 0; rf < 2; ++rf) {
            floatx4 s = {};
            s = __builtin_amdgcn_mfma_f32_16x16x32_f16(aq[rf][0], bk0, s, 0, 0, 0);
            s = __builtin_amdgcn_mfma_f32_16x16x32_f16(aq[rf][1], bk1, s, 0, 0, 0);
#pragma unroll
            for (int r = 0; r < 4; ++r) {
                int row = rf * 16 + quad * 4 + r;
                float e = __expf(fminf(s[r] * 0.125f, 10.0f));   // exp(10)=22026 < fp16 max
                *(_Float16*)(Eb + esw(row, (c0 + l15) * 2)) = (_Float16)e;
            }
        }
    }
    __syncthreads();

    // --- rowsum + threshold: p = relu(e/l - 1e-3), in place ---
    {
        int row = tid >> 3, seg = tid & 7;   // 8 threads per row, 128 cols each
        float l = 0.f;
#pragma unroll
        for (int i = 0; i < 16; ++i) {
            half8 hv = *(const half8*)(Eb + esw(row, (seg * 128 + i * 8) * 2));
#pragma unroll
            for (int j = 0; j < 8; ++j) l += (float)hv[j];
        }
        l += __shfl_xor(l, 1, 8);
        l += __shfl_xor(l, 2, 8);
        l += __shfl_xor(l, 4, 8);
        float inv = 1.0f / l;
#pragma unroll
        for (int i = 0; i < 16; ++i) {
            half8* p = (half8*)(Eb + esw(row, (seg * 128 + i * 8) * 2));
            half8 hv = *p;
#pragma unroll
            for (int j = 0; j < 8; ++j) {
                float v = (float)hv[j] * inv - 0.001f;
                hv[j] = (_Float16)(v > 0.f ? v : 0.f);
            }
            *p = hv;
        }
    }
    __syncthreads();

    // --- y_partial = P[:, w*256 : w*256+256] @ V ---
    floatx4 acc[2][4] = {};
#pragma unroll 2
    for (int ks8 = 0; ks8 < 8; ++ks8) {
        int kk = W * 256 + ks8 * 32;
        half8 ap[2];
#pragma unroll
        for (int rf = 0; rf < 2; ++rf)
            ap[rf] = *(const half8*)(Eb + esw(rf * 16 + l15, (kk + quad * 8) * 2));
        half8 bv[4];
#pragma unroll
        for (int cf = 0; cf < 4; ++cf)
            bv[cf] = *(const half8*)(vT + (size_t)(bh * 64 + cf * 16 + l15) * 1024 + kk + quad * 8);
#pragma unroll
        for (int rf = 0; rf < 2; ++rf)
#pragma unroll
            for (int cf = 0; cf < 4; ++cf)
                acc[rf][cf] = __builtin_amdgcn_mfma_f32_16x16x32_f16(ap[rf], bv[cf], acc[rf][cf], 0, 0, 0);
    }
    __syncthreads();   // everyone done reading E before reuse

    // --- cross-wave reduction of partials via LDS reuse ---
    float* red = (float*)E;    // 4 waves x 32x64 fp32 = 32KB
#pragma unroll
    for (int rf = 0; rf < 2; ++rf)
#pragma unroll
        for (int cf = 0; cf < 4; ++cf)
#pragma unroll
            for (int r = 0; r < 4; ++r) {
                int row = rf * 16 + quad * 4 + r;
                int col = cf * 16 + l15;
                red[W * 2048 + row * 64 + col] = acc[rf][cf][r];
            }
    __syncthreads();
#pragma unroll
    for (int i = 0; i < 8; ++i) {
        int e = i * 256 + tid;
        int r = e >> 6, c = e & 63;
        float s = red[e] + red[2048 + e] + red[4096 + e] + red[6144 + e];
        y[(size_t)(b * 1024 + q0 + r) * 1024 + h * 64 + c] = (_Float16)s;
    }
}

// ------------------------------- launcher -------------------------------
extern "C" void kernel_launch(void* const* d_in, const int* in_sizes, int n_in,
                              void* d_out, int out_size, void* d_ws, size_t ws_size,
                              hipStream_t stream) {
    const float* x  = (const float*)d_in[0];
    const float* wa = (const float*)d_in[1];
    const float* ba = (const float*)d_in[2];
    const float* wp = (const float*)d_in[3];
    const float* bp = (const float*)d_in[4];
    float* out = (float*)d_out;

    char* ws = (char*)d_ws;
    _Float16* qkv = (_Float16*)(ws);                    // 48 MiB
    _Float16* vT  = (_Float16*)(ws + 50331648);         // 16 MiB
    _Float16* xh  = (_Float16*)(ws + 67108864);         // 16 MiB (reused as y)
    _Float16* waT = (_Float16*)(ws + 83886080);         // 6 MiB
    _Float16* wpT = (_Float16*)(ws + 90177536);         // 2 MiB

    conv_x<<<4096, 256, 0, stream>>>((const float4*)x, xh, 8388608 / 4);
    tconv<<<dim3(48, 16), 256, 0, stream>>>(wa, waT, 1024, 3072);
    tconv<<<dim3(16, 16), 256, 0, stream>>>(wp, wpT, 1024, 1024);
    gemm_tn<true><<<dim3(24, 64), 256, 0, stream>>>(xh, waT, ba, (void*)qkv, 3072);
    vtrans<<<dim3(16, 128), 256, 0, stream>>>(qkv, vT);
    attn<<<dim3(32, 128), 256, 0, stream>>>(qkv, vT, xh);
    gemm_tn<false><<<dim3(8, 64), 256, 0, stream>>>(xh, wpT, bp, (void*)out, 1024);
}

// Round 2
// 336.204 us; speedup vs baseline: 1.0870x; 1.0870x over previous
//
#include <hip/hip_runtime.h>

// TreeAttentionV2: B=8, T=1024, C=1024 (L=4,R=256), H=16, hd=64.
// Pipeline (all fp16 MFMA, fp32 accumulate):
//   1. conv_x:      x fp32 (8192x1024) -> xh fp16
//   2. tconv:       w_attn fp32 (1024x3072) -> waT fp16 (3072x1024)   [B^T for GEMM]
//   3. tconv:       w_proj fp32 (1024x1024) -> wpT fp16 (1024x1024)
//   4. gemm<f16>:   qkv = xh @ waT^T + b_attn  -> fp16 (8192x3072)
//   5. vtrans:      v section -> vT (128 heads)(64 x 1024)            [V^T for PV MFMA]
//   6. attn v2:     512 thr / 8 waves; S^T = K.Q^T so C-layout packs 4 consecutive
//                   k-cols per lane -> vectorized b64 E-stores; conflict-free rowsum;
//                   P@V with per-wave 128-col k-slices; LDS-reduce partials.
//   7. gemm<f32>:   out = y @ wpT^T + b_proj -> fp32 d_out
//
// Workspace layout (needs >= 92,274,688 B):
//   [0, 48M)   qkv fp16
//   [48M,64M)  vT  fp16
//   [64M,80M)  xh fp16 (reused as y after gemm1 consumes it)
//   [80M,86M)  waT fp16
//   [86M,88M)  wpT fp16

typedef _Float16 half8 __attribute__((ext_vector_type(8)));
typedef _Float16 half4_t __attribute__((ext_vector_type(4)));
typedef float floatx4 __attribute__((ext_vector_type(4)));

__device__ __forceinline__ void gl2lds16(const void* gsrc, void* lds) {
    __builtin_amdgcn_global_load_lds(
        (const __attribute__((address_space(1))) unsigned int*)gsrc,
        (__attribute__((address_space(3))) unsigned int*)lds,
        16, 0, 0);
}

// ---------------- elementwise convert fp32 -> fp16 ----------------
__global__ __launch_bounds__(256) void conv_x(const float4* __restrict__ in,
                                              _Float16* __restrict__ out, int n4) {
    int idx = blockIdx.x * blockDim.x + threadIdx.x;
    int stride = gridDim.x * blockDim.x;
    for (int i = idx; i < n4; i += stride) {
        float4 v = in[i];
        half4_t h = { (_Float16)v.x, (_Float16)v.y, (_Float16)v.z, (_Float16)v.w };
        *(half4_t*)(out + (size_t)i * 4) = h;
    }
}

// ------------- transpose + convert: out[n][k] = in[k][n] ----------
__global__ __launch_bounds__(256) void tconv(const float* __restrict__ in,
                                             _Float16* __restrict__ out, int R, int C) {
    __shared__ _Float16 t[64 * 65];
    int bx = blockIdx.x, by = blockIdx.y;
#pragma unroll
    for (int it = 0; it < 16; ++it) {
        int idx = it * 256 + threadIdx.x;
        int r = idx >> 6, c = idx & 63;
        t[c * 65 + r] = (_Float16)in[(size_t)(by * 64 + r) * C + bx * 64 + c];
    }
    __syncthreads();
#pragma unroll
    for (int it = 0; it < 16; ++it) {
        int idx = it * 256 + threadIdx.x;
        int rn = idx >> 6, ck = idx & 63;
        out[(size_t)(bx * 64 + rn) * R + by * 64 + ck] = t[rn * 65 + ck];
    }
}

// ------------- V transpose: vT[bh*64+d][t] = qkv[b,t, 2048+h*64+d] -------------
__global__ __launch_bounds__(256) void vtrans(const _Float16* __restrict__ qkv,
                                              _Float16* __restrict__ vT) {
    __shared__ _Float16 t[64 * 65];
    int t0 = blockIdx.x * 64;
    int bh = blockIdx.y;
    int b = bh >> 4, h = bh & 15;
#pragma unroll
    for (int it = 0; it < 16; ++it) {
        int idx = it * 256 + threadIdx.x;
        int tt = idx >> 6, d = idx & 63;
        t[d * 65 + tt] = qkv[(size_t)(b * 1024 + t0 + tt) * 3072 + 2048 + h * 64 + d];
    }
    __syncthreads();
#pragma unroll
    for (int it = 0; it < 16; ++it) {
        int idx = it * 256 + threadIdx.x;
        int dd = idx >> 6, tt = idx & 63;
        vT[(size_t)(bh * 64 + dd) * 1024 + t0 + tt] = t[dd * 65 + tt];
    }
}

// ------------- m97-style GEMM: C(MxN) = A(MxK) * BT(NxK)^T + bias -------------
template <bool F16OUT>
__global__ __launch_bounds__(256) void gemm_tn(const _Float16* __restrict__ A,
                                               const _Float16* __restrict__ BT,
                                               const float* __restrict__ bias,
                                               void* __restrict__ Cout, int N) {
    constexpr int K = 1024;
    __shared__ __attribute__((aligned(16))) _Float16 sA[128 * 32];
    __shared__ __attribute__((aligned(16))) _Float16 sB[128 * 32];
    int tid = threadIdx.x;
    int W = tid >> 6, lane = tid & 63, quad = lane >> 4, l15 = lane & 15;
    int m0 = blockIdx.y * 128, n0 = blockIdx.x * 128;
    int wr = (W >> 1) * 64, wc = (W & 1) * 64;
    floatx4 acc[4][4] = {};

    for (int kt = 0; kt < K / 32; ++kt) {
        int k0 = kt * 32;
#pragma unroll
        for (int rho = 0; rho < 2; ++rho) {
            int lin = rho * 256 + tid;                 // 16B chunk id, tile row-major
            const _Float16* gA = A + (size_t)(m0 + (lin >> 2)) * K + k0 + (lin & 3) * 8;
            const _Float16* gB = BT + (size_t)(n0 + (lin >> 2)) * K + k0 + (lin & 3) * 8;
            int ldsoff = __builtin_amdgcn_readfirstlane((rho * 256 + W * 64) * 16);
            gl2lds16(gA, (char*)sA + ldsoff);
            gl2lds16(gB, (char*)sB + ldsoff);
        }
        __syncthreads();
        half8 a[4], b[4];
#pragma unroll
        for (int rf = 0; rf < 4; ++rf)
            a[rf] = *(const half8*)(sA + (wr + rf * 16 + l15) * 32 + quad * 8);
#pragma unroll
        for (int cf = 0; cf < 4; ++cf)
            b[cf] = *(const half8*)(sB + (wc + cf * 16 + l15) * 32 + quad * 8);
#pragma unroll
        for (int rf = 0; rf < 4; ++rf)
#pragma unroll
            for (int cf = 0; cf < 4; ++cf)
                acc[rf][cf] = __builtin_amdgcn_mfma_f32_16x16x32_f16(a[rf], b[cf], acc[rf][cf], 0, 0, 0);
        __syncthreads();
    }
#pragma unroll
    for (int cf = 0; cf < 4; ++cf) {
        int gn = n0 + wc + cf * 16 + l15;
        float bv = bias[gn];
#pragma unroll
        for (int rf = 0; rf < 4; ++rf) {
            int gmBase = m0 + wr + rf * 16 + quad * 4;
#pragma unroll
            for (int r = 0; r < 4; ++r) {
                float v = acc[rf][cf][r] + bv;
                size_t off = (size_t)(gmBase + r) * N + gn;
                if (F16OUT) ((_Float16*)Cout)[off] = (_Float16)v;
                else        ((float*)Cout)[off] = v;
            }
        }
    }
}

// ------------------------------- attention v2 -------------------------------
// grid (32 q-tiles, 128 bh), 512 threads = 8 waves; wave w owns k-cols [w*128, w*128+128)
// LDS: E = 32 q-rows x 1024 k-cols fp16 (64KB), xor-swizzled (16B granular) rows.
__device__ __forceinline__ int esw(int row, int colByte) {
    return row * 2048 + (colByte ^ ((row & 7) << 4));
}

__global__ __launch_bounds__(512, 4) void attn(const _Float16* __restrict__ qkv,
                                               const _Float16* __restrict__ vT,
                                               _Float16* __restrict__ y) {
    __shared__ __attribute__((aligned(16))) _Float16 E[32 * 1024];
    char* Eb = (char*)E;
    int tid = threadIdx.x;
    int W = tid >> 6, lane = tid & 63, quad = lane >> 4, l15 = lane & 15;
    int qt = blockIdx.x, bh = blockIdx.y;
    int b = bh >> 4, h = bh & 15;
    int q0 = qt * 32;

    // --- Q as B-fragments (B[k=quad*8+j][n=l15]): n = q-row, k = d ---
    half8 bq[2][2];
#pragma unroll
    for (int nf = 0; nf < 2; ++nf)
#pragma unroll
        for (int ks = 0; ks < 2; ++ks)
            bq[nf][ks] = *(const half8*)(qkv + (size_t)(b * 1024 + q0 + nf * 16 + l15) * 3072 +
                                         h * 64 + ks * 32 + quad * 8);

    // --- S^T = K.Q^T (scaled), e = exp(s) -> E[q][k] as packed b64 stores ---
    // C-layout of S^T tile: col(l15) = q, row(quad*4+r) = k  -> 4 consecutive k per lane.
#pragma unroll 4
    for (int mt = 0; mt < 8; ++mt) {
        int tk = W * 128 + mt * 16 + l15;
        const _Float16* kp = qkv + (size_t)(b * 1024 + tk) * 3072 + 1024 + h * 64 + quad * 8;
        half8 ak0 = *(const half8*)(kp);
        half8 ak1 = *(const half8*)(kp + 32);
#pragma unroll
        for (int nf = 0; nf < 2; ++nf) {
            floatx4 s = {};
            s = __builtin_amdgcn_mfma_f32_16x16x32_f16(ak0, bq[nf][0], s, 0, 0, 0);
            s = __builtin_amdgcn_mfma_f32_16x16x32_f16(ak1, bq[nf][1], s, 0, 0, 0);
            half4_t h4;
#pragma unroll
            for (int r = 0; r < 4; ++r)
                h4[r] = (_Float16)__expf(fminf(s[r] * 0.125f, 10.0f));  // exp(10)=22026 < fp16 max
            int q = nf * 16 + l15;
            int kbyte = (W * 128 + mt * 16 + quad * 4) * 2;
            *(half4_t*)(Eb + q * 2048 + (kbyte ^ ((q & 7) << 4))) = h4;
        }
    }
    __syncthreads();

    // --- rowsum + threshold: p = relu(e/l - 1e-3), in place. 16 threads/row. ---
    {
        int row = tid >> 4, seg = tid & 15;  // seg = lane bits 0..3
        float l = 0.f;
#pragma unroll
        for (int c = 0; c < 8; ++c) {
            half8 hv = *(const half8*)(Eb + esw(row, c * 256 + seg * 16));
#pragma unroll
            for (int j = 0; j < 8; ++j) l += (float)hv[j];
        }
        l += __shfl_xor(l, 1);
        l += __shfl_xor(l, 2);
        l += __shfl_xor(l, 4);
        l += __shfl_xor(l, 8);
        float inv = 1.0f / l;
#pragma unroll
        for (int c = 0; c < 8; ++c) {
            half8* p = (half8*)(Eb + esw(row, c * 256 + seg * 16));
            half8 hv = *p;
#pragma unroll
            for (int j = 0; j < 8; ++j) {
                float v = (float)hv[j] * inv - 0.001f;
                hv[j] = (_Float16)(v > 0.f ? v : 0.f);
            }
            *p = hv;
        }
    }
    __syncthreads();

    // --- y_partial = P[:, W*128 : W*128+128] @ V ---
    floatx4 acc[2][4] = {};
#pragma unroll
    for (int kt = 0; kt < 4; ++kt) {
        int kk = W * 128 + kt * 32;
        half8 ap[2];
#pragma unroll
        for (int rf = 0; rf < 2; ++rf)
            ap[rf] = *(const half8*)(Eb + esw(rf * 16 + l15, (kk + quad * 8) * 2));
        half8 bv[4];
#pragma unroll
        for (int cf = 0; cf < 4; ++cf)
            bv[cf] = *(const half8*)(vT + (size_t)(bh * 64 + cf * 16 + l15) * 1024 + kk + quad * 8);
#pragma unroll
        for (int rf = 0; rf < 2; ++rf)
#pragma unroll
            for (int cf = 0; cf < 4; ++cf)
                acc[rf][cf] = __builtin_amdgcn_mfma_f32_16x16x32_f16(ap[rf], bv[cf], acc[rf][cf], 0, 0, 0);
    }
    __syncthreads();   // everyone done reading E before reuse

    // --- cross-wave reduction of 8 partials via LDS reuse (exactly 64KB fp32) ---
    float* red = (float*)E;
#pragma unroll
    for (int rf = 0; rf < 2; ++rf)
#pragma unroll
        for (int cf = 0; cf < 4; ++cf)
#pragma unroll
            for (int r = 0; r < 4; ++r) {
                int row = rf * 16 + quad * 4 + r;
                int col = cf * 16 + l15;
                red[W * 2048 + row * 64 + col] = acc[rf][cf][r];
            }
    __syncthreads();
    {
        int e4 = tid * 4;                 // 512 thr x 4 elems = 2048 = 32x64
        int r = e4 >> 6, c = e4 & 63;
        floatx4 s = {};
#pragma unroll
        for (int w = 0; w < 8; ++w) s += *(const floatx4*)(red + w * 2048 + e4);
        half4_t hv = { (_Float16)s[0], (_Float16)s[1], (_Float16)s[2], (_Float16)s[3] };
        *(half4_t*)(y + (size_t)(b * 1024 + q0 + r) * 1024 + h * 64 + c) = hv;
    }
}

// ------------------------------- launcher -------------------------------
extern "C" void kernel_launch(void* const* d_in, const int* in_sizes, int n_in,
                              void* d_out, int out_size, void* d_ws, size_t ws_size,
                              hipStream_t stream) {
    const float* x  = (const float*)d_in[0];
    const float* wa = (const float*)d_in[1];
    const float* ba = (const float*)d_in[2];
    const float* wp = (const float*)d_in[3];
    const float* bp = (const float*)d_in[4];
    float* out = (float*)d_out;

    char* ws = (char*)d_ws;
    _Float16* qkv = (_Float16*)(ws);                    // 48 MiB
    _Float16* vT  = (_Float16*)(ws + 50331648);         // 16 MiB
    _Float16* xh  = (_Float16*)(ws + 67108864);         // 16 MiB (reused as y)
    _Float16* waT = (_Float16*)(ws + 83886080);         // 6 MiB
    _Float16* wpT = (_Float16*)(ws + 90177536);         // 2 MiB

    conv_x<<<4096, 256, 0, stream>>>((const float4*)x, xh, 8388608 / 4);
    tconv<<<dim3(48, 16), 256, 0, stream>>>(wa, waT, 1024, 3072);
    tconv<<<dim3(16, 16), 256, 0, stream>>>(wp, wpT, 1024, 1024);
    gemm_tn<true><<<dim3(24, 64), 256, 0, stream>>>(xh, waT, ba, (void*)qkv, 3072);
    vtrans<<<dim3(16, 128), 256, 0, stream>>>(qkv, vT);
    attn<<<dim3(32, 128), 512, 0, stream>>>(qkv, vT, xh);
    gemm_tn<false><<<dim3(8, 64), 256, 0, stream>>>(xh, wpT, bp, (void*)out, 1024);
}